// Round 10
// baseline (382.845 us; speedup 1.0000x reference)
//
#include <hip/hip_runtime.h>
#include <hip/hip_bf16.h>

#define N_NODES 50000
#define N_EDGES 800000
#define ETOT (N_EDGES + N_NODES)
#define N_GRAPHS 64
#define HEADS 4
#define IN_CH 128
#define HID 64
#define F1 256  // HEADS*HID
#define OUT_CH 32
#define F2 128  // HEADS*OUT_CH
#define POOL_SPLITS 16
#define SCAN_B 256
#define SCAN_NB ((N_NODES + SCAN_B - 1) / SCAN_B)  // 196

typedef unsigned short ushortT;
typedef unsigned int uintT;
typedef short v8s __attribute__((ext_vector_type(8)));
typedef float v4f __attribute__((ext_vector_type(4)));

__device__ __forceinline__ ushortT f2bf(float f) {
    union { float f; unsigned int i; } v; v.f = f;
    unsigned int x = v.i;
    unsigned int r = (x + 0x7fffu + ((x >> 16) & 1u)) >> 16;  // RNE
    return (ushortT)r;
}
__device__ __forceinline__ float bf_lo(uintT w) {
    union { unsigned int i; float f; } v; v.i = w << 16; return v.f;
}
__device__ __forceinline__ float bf_hi(uintT w) {
    union { unsigned int i; float f; } v; v.i = w & 0xffff0000u; return v.f;
}

// ---- CSR build over dst (shared by both GAT layers) ----
__global__ void k_count(const int* __restrict__ ei, int* __restrict__ counts) {
    int e = blockIdx.x * blockDim.x + threadIdx.x;
    if (e >= ETOT) return;
    int dst = (e < N_EDGES) ? ei[N_EDGES + e] : (e - N_EDGES);
    atomicAdd(&counts[dst], 1);
}

// ---- parallel 3-phase exclusive scan ----
__global__ void k_scan1(const int* __restrict__ counts, int* __restrict__ offs,
                        int* __restrict__ bsum) {
    __shared__ int sh[SCAN_B];
    int b = blockIdx.x, t = threadIdx.x;
    int i = b * SCAN_B + t;
    int v = (i < N_NODES) ? counts[i] : 0;
    sh[t] = v;
    __syncthreads();
    for (int o = 1; o < SCAN_B; o <<= 1) {
        int add = (t >= o) ? sh[t - o] : 0;
        __syncthreads();
        sh[t] += add;
        __syncthreads();
    }
    if (i < N_NODES) offs[i] = sh[t] - v;
    if (t == SCAN_B - 1) bsum[b] = sh[t];
}

__global__ void k_scan2(const int* __restrict__ bsum, int* __restrict__ bbase,
                        int* __restrict__ offs) {
    __shared__ int sh[SCAN_B];
    int t = threadIdx.x;
    int v = (t < SCAN_NB) ? bsum[t] : 0;
    sh[t] = v;
    __syncthreads();
    for (int o = 1; o < SCAN_B; o <<= 1) {
        int add = (t >= o) ? sh[t - o] : 0;
        __syncthreads();
        sh[t] += add;
        __syncthreads();
    }
    if (t < SCAN_NB) bbase[t] = sh[t] - v;
    if (t == SCAN_B - 1) offs[N_NODES] = sh[t];
}

__global__ void k_scan3(int* __restrict__ offs, const int* __restrict__ bbase) {
    int i = blockIdx.x * SCAN_B + threadIdx.x;
    if (i < N_NODES) offs[i] += bbase[blockIdx.x];
}

__global__ void k_scatter(const int* __restrict__ ei, const int* __restrict__ offsets,
                          int* __restrict__ cursor, int* __restrict__ csr_src) {
    int e = blockIdx.x * blockDim.x + threadIdx.x;
    if (e >= ETOT) return;
    int src, dst;
    if (e < N_EDGES) { src = ei[e]; dst = ei[N_EDGES + e]; }
    else             { src = dst = e - N_EDGES; }
    int pos = offsets[dst] + atomicAdd(&cursor[dst], 1);
    csr_src[pos] = src;
}

// ---- pack W (fp32 [K][N]) into bf16 B-fragment order for 16x16x32 MFMA ----
template <int FIN, int FOUT>
__global__ void k_packW(const float* __restrict__ W, ushortT* __restrict__ pW) {
    constexpr int KC = FIN / 32;
    int tid = blockIdx.x * blockDim.x + threadIdx.x;
    if (tid >= FIN * FOUT / 8) return;
    int lane = tid & 63;
    int g = tid >> 6;
    int kc = g % KC, nt = g / KC;
    int n = nt * 16 + (lane & 15);
    int kbase = kc * 32 + (lane >> 4) * 8;
    union { uint4 q; ushortT u[8]; } pk;
#pragma unroll
    for (int j = 0; j < 8; j++) pk.u[j] = f2bf(W[(kbase + j) * FOUT + n]);
    ((uint4*)pW)[tid] = pk.q;
}

// ---- MFMA GEMM: out[r][n] = sum_k A[r][k]*W[k][n], bf16 out ----
// No LDS, no barriers: B-fragments streamed straight from L2 (W is tiny and
// shared by all blocks); occupancy VGPR-bound instead of 64KB-LDS-bound.
template <int FIN, int FOUT, bool ABF16>
__global__ __launch_bounds__(256) void k_gemm_mfma(const void* __restrict__ A,
                                                   const uint4* __restrict__ Wp,
                                                   ushortT* __restrict__ out, int nrows) {
    constexpr int KC = FIN / 32;
    constexpr int NT = FOUT / 16;
    int tid = threadIdx.x;
    int wave = tid >> 6, lane = tid & 63;
    long row0 = (long)blockIdx.x * 64 + wave * 16;
    if (row0 >= nrows) return;  // wave-uniform (nrows % 16 == 0)
    int m = lane & 15, b = lane >> 4;

    v8s afrag[KC];
    if (ABF16) {
        const ushortT* Ab = (const ushortT*)A;
#pragma unroll
        for (int kc = 0; kc < KC; kc++) {
            union { v8s v; uint4 q; } u;
            u.q = *(const uint4*)(Ab + (row0 + m) * FIN + kc * 32 + b * 8);
            afrag[kc] = u.v;
        }
    } else {
        const float* Af = (const float*)A;
#pragma unroll
        for (int kc = 0; kc < KC; kc++) {
            union { v8s v; ushortT u[8]; } u;
            const float* p = Af + (row0 + m) * FIN + kc * 32 + b * 8;
#pragma unroll
            for (int j = 0; j < 8; j++) u.u[j] = f2bf(p[j]);
            afrag[kc] = u.v;
        }
    }

#pragma unroll
    for (int nt = 0; nt < NT; nt++) {
        v4f c = {0.f, 0.f, 0.f, 0.f};
#pragma unroll
        for (int kc = 0; kc < KC; kc++) {
            union { v8s v; uint4 q; } bu;
            bu.q = Wp[(nt * KC + kc) * 64 + lane];
            c = __builtin_amdgcn_mfma_f32_16x16x32_bf16(afrag[kc], bu.v, c, 0, 0, 0);
        }
        // C/D: col = lane&15, row = (lane>>4)*4 + reg   [measured m89/m91]
        long r = row0 + b * 4;
        int col = nt * 16 + m;
#pragma unroll
        for (int reg = 0; reg < 4; reg++)
            out[(r + reg) * FOUT + col] = f2bf(c[reg]);
    }
}

// ---- per-node per-head attention terms s,d (bf16 h input) ----
template <int H, int C>
__global__ void k_sd(const ushortT* __restrict__ hb, const float* __restrict__ asrc,
                     const float* __restrict__ adst,
                     float* __restrict__ s, float* __restrict__ d) {
    int tid = blockIdx.x * blockDim.x + threadIdx.x;
    if (tid >= N_NODES * H) return;
    int n = tid / H, h = tid - n * H;
    const uintT* row = (const uintT*)(hb + (long)n * (H * C) + h * C);
    float ss = 0.f, dd = 0.f;
#pragma unroll 4
    for (int c2 = 0; c2 < C / 2; c2++) {
        uintT w = row[c2];
        float v0 = bf_lo(w), v1 = bf_hi(w);
        ss += v0 * asrc[h * C + 2 * c2] + v1 * asrc[h * C + 2 * c2 + 1];
        dd += v0 * adst[h * C + 2 * c2] + v1 * adst[h * C + 2 * c2 + 1];
    }
    s[tid] = ss; d[tid] = dd;
}

// ---- fused segment-softmax + aggregation: TWO nodes per wave, no barriers ----
// Each wave owns nodes (2p, 2p+1) and a private LDS slice; the accumulate loop
// interleaves both nodes' edge streams -> 2 independent gathers in flight
// (attacks miss latency; traffic unchanged). Per-node arithmetic order is
// identical to the single-node version. Intra-wave LDS visibility via
// s_waitcnt lgkmcnt(0) only (lockstep wave). exp once per (edge,head); no max
// pass (|e| <~ 6: fp32-safe; alpha mathematically identical).
template <int H, int C, int VEC, bool OUT_BF16, int WPB, int CHUNK>
__global__ __launch_bounds__(64 * WPB) void k_agg(
        const ushortT* __restrict__ hb, const float* __restrict__ s,
        const float* __restrict__ d, const int* __restrict__ offsets,
        const int* __restrict__ csr_src, const float* __restrict__ bias,
        void* __restrict__ xout) {
    static_assert(H == 4, "H=4 assumed");
    constexpr int F = H * C;
    constexpr int TPN = F / VEC;
    static_assert(TPN == 64, "one wave per node");
    __shared__ int   lsrc[WPB][2][CHUNK];
    __shared__ float lex[WPB][2][CHUNK * H];
    int wv = threadIdx.x >> 6;
    int pair = blockIdx.x * WPB + wv;
    int nA = pair * 2;                 // nA+1 < N_NODES (N even, exact grid)
    if (nA >= N_NODES) return;
    int nB = nA + 1;
    int t = threadIdx.x & 63;
    int h = t / (C / VEC);
    int begA = offsets[nA], endA = offsets[nA + 1];
    int begB = offsets[nB], endB = offsets[nB + 1];
    float4 dA = *(const float4*)(d + nA * 4);
    float4 dB = *(const float4*)(d + nB * 4);

    float sumexA = 0.f, sumexB = 0.f;
    float accA[VEC], accB[VEC];
#pragma unroll
    for (int j = 0; j < VEC; j++) { accA[j] = 0.f; accB[j] = 0.f; }

    const uint2* hb2 = (const uint2*)hb;
    const uintT* hb1 = (const uintT*)hb;

    int baseA = begA, baseB = begB;
    while (baseA < endA || baseB < endB) {
        int cntA = endA - baseA; cntA = cntA < 0 ? 0 : (cntA > CHUNK ? CHUNK : cntA);
        int cntB = endB - baseB; cntB = cntB < 0 ? 0 : (cntB > CHUNK ? CHUNK : cntB);
        // stage: lane t handles edge base+t of each node (CHUNK == 64)
        if (t < cntA) {
            int sn = csr_src[baseA + t];
            lsrc[wv][0][t] = sn;
            float4 sv = *(const float4*)(s + sn * 4);
            float e0 = sv.x + dA.x; e0 = e0 > 0.f ? e0 : 0.2f * e0;
            float e1 = sv.y + dA.y; e1 = e1 > 0.f ? e1 : 0.2f * e1;
            float e2 = sv.z + dA.z; e2 = e2 > 0.f ? e2 : 0.2f * e2;
            float e3 = sv.w + dA.w; e3 = e3 > 0.f ? e3 : 0.2f * e3;
            float4 exv = { __expf(e0), __expf(e1), __expf(e2), __expf(e3) };
            *(float4*)&lex[wv][0][t * 4] = exv;
        }
        if (t < cntB) {
            int sn = csr_src[baseB + t];
            lsrc[wv][1][t] = sn;
            float4 sv = *(const float4*)(s + sn * 4);
            float e0 = sv.x + dB.x; e0 = e0 > 0.f ? e0 : 0.2f * e0;
            float e1 = sv.y + dB.y; e1 = e1 > 0.f ? e1 : 0.2f * e1;
            float e2 = sv.z + dB.z; e2 = e2 > 0.f ? e2 : 0.2f * e2;
            float e3 = sv.w + dB.w; e3 = e3 > 0.f ? e3 : 0.2f * e3;
            float4 exv = { __expf(e0), __expf(e1), __expf(e2), __expf(e3) };
            *(float4*)&lex[wv][1][t * 4] = exv;
        }
        // intra-wave LDS write->read ordering (no block barrier needed)
        asm volatile("s_waitcnt lgkmcnt(0)" ::: "memory");

        int cmn = cntA < cntB ? cntA : cntB;
#pragma unroll 4
        for (int i = 0; i < cmn; i++) {
            float exA = lex[wv][0][i * H + h];
            int snA = lsrc[wv][0][i];
            float exB = lex[wv][1][i * H + h];
            int snB = lsrc[wv][1][i];
            sumexA += exA; sumexB += exB;
            if (VEC == 4) {
                uint2 wA = hb2[(long)snA * TPN + t];
                uint2 wB = hb2[(long)snB * TPN + t];
                accA[0] += exA * bf_lo(wA.x); accA[1] += exA * bf_hi(wA.x);
                accA[2] += exA * bf_lo(wA.y); accA[3] += exA * bf_hi(wA.y);
                accB[0] += exB * bf_lo(wB.x); accB[1] += exB * bf_hi(wB.x);
                accB[2] += exB * bf_lo(wB.y); accB[3] += exB * bf_hi(wB.y);
            } else {
                uintT wA = hb1[(long)snA * TPN + t];
                uintT wB = hb1[(long)snB * TPN + t];
                accA[0] += exA * bf_lo(wA); accA[1] += exA * bf_hi(wA);
                accB[0] += exB * bf_lo(wB); accB[1] += exB * bf_hi(wB);
            }
        }
#pragma unroll 4
        for (int i = cmn; i < cntA; i++) {
            float ex = lex[wv][0][i * H + h];
            int sn = lsrc[wv][0][i];
            sumexA += ex;
            if (VEC == 4) {
                uint2 w = hb2[(long)sn * TPN + t];
                accA[0] += ex * bf_lo(w.x); accA[1] += ex * bf_hi(w.x);
                accA[2] += ex * bf_lo(w.y); accA[3] += ex * bf_hi(w.y);
            } else {
                uintT w = hb1[(long)sn * TPN + t];
                accA[0] += ex * bf_lo(w); accA[1] += ex * bf_hi(w);
            }
        }
#pragma unroll 4
        for (int i = cmn; i < cntB; i++) {
            float ex = lex[wv][1][i * H + h];
            int sn = lsrc[wv][1][i];
            sumexB += ex;
            if (VEC == 4) {
                uint2 w = hb2[(long)sn * TPN + t];
                accB[0] += ex * bf_lo(w.x); accB[1] += ex * bf_hi(w.x);
                accB[2] += ex * bf_lo(w.y); accB[3] += ex * bf_hi(w.y);
            } else {
                uintT w = hb1[(long)sn * TPN + t];
                accB[0] += ex * bf_lo(w); accB[1] += ex * bf_hi(w);
            }
        }
        // keep next chunk's LDS writes from overtaking this chunk's reads
        asm volatile("" ::: "memory");
        baseA += CHUNK; baseB += CHUNK;
    }

    float invA = 1.f / (sumexA + 1e-16f);
    float invB = 1.f / (sumexB + 1e-16f);
    float oA[VEC], oB[VEC];
#pragma unroll
    for (int j = 0; j < VEC; j++) {
        oA[j] = fmaxf(accA[j] * invA + bias[t * VEC + j], 0.f);
        oB[j] = fmaxf(accB[j] * invB + bias[t * VEC + j], 0.f);
    }
    if (OUT_BF16) {
        if (VEC == 4) {
            uint2 pA, pB;
            pA.x = (uintT)f2bf(oA[0]) | ((uintT)f2bf(oA[1]) << 16);
            pA.y = (uintT)f2bf(oA[2]) | ((uintT)f2bf(oA[3]) << 16);
            pB.x = (uintT)f2bf(oB[0]) | ((uintT)f2bf(oB[1]) << 16);
            pB.y = (uintT)f2bf(oB[2]) | ((uintT)f2bf(oB[3]) << 16);
            ((uint2*)xout)[(long)nA * TPN + t] = pA;
            ((uint2*)xout)[(long)nB * TPN + t] = pB;
        } else {
            ((uintT*)xout)[(long)nA * TPN + t] = (uintT)f2bf(oA[0]) | ((uintT)f2bf(oA[1]) << 16);
            ((uintT*)xout)[(long)nB * TPN + t] = (uintT)f2bf(oB[0]) | ((uintT)f2bf(oB[1]) << 16);
        }
    } else {
        float* xo = (float*)xout;
#pragma unroll
        for (int j = 0; j < VEC; j++) {
            xo[(long)nA * F + t * VEC + j] = oA[j];
            xo[(long)nB * F + t * VEC + j] = oB[j];
        }
    }
}

// ---- graph boundaries via binary search on sorted batch ----
__global__ void k_bounds(const int* __restrict__ batch, int* __restrict__ bounds) {
    int g = threadIdx.x;
    if (g > N_GRAPHS) return;
    int lo = 0, hi = N_NODES;
    while (lo < hi) {
        int mid = (lo + hi) >> 1;
        if (batch[mid] < g) lo = mid + 1; else hi = mid;
    }
    bounds[g] = lo;
}

// ---- pool partials: block (g,s) sums a contiguous node slice, no atomics ----
__global__ void k_pool_partial(const float* __restrict__ x3, const int* __restrict__ bounds,
                               float* __restrict__ partial) {
    int g = blockIdx.x, s = blockIdx.y;
    int t = threadIdx.x;
    int n0 = bounds[g], n1 = bounds[g + 1];
    int len = n1 - n0;
    int a = n0 + (int)((long)len * s / POOL_SPLITS);
    int b = n0 + (int)((long)len * (s + 1) / POOL_SPLITS);
    float acc = 0.f;
    for (int n = a; n < b; n++) acc += x3[(long)n * F2 + t];
    partial[((long)g * POOL_SPLITS + s) * F2 + t] = acc;
}

// ---- head: block per graph — reduce partials, mean, logits, softmax ----
__global__ void k_head(const float* __restrict__ partial, const int* __restrict__ bounds,
                       const float* __restrict__ Wout, const float* __restrict__ bout,
                       float* __restrict__ out) {
    __shared__ float red0[F2], red1[F2];
    int g = blockIdx.x;
    int t = threadIdx.x;
    int cntN = bounds[g + 1] - bounds[g];
    float cnt = fmaxf((float)cntN, 1.0f);
    float sum = 0.f;
    for (int s = 0; s < POOL_SPLITS; s++)
        sum += partial[((long)g * POOL_SPLITS + s) * F2 + t];
    float p = sum / cnt;
    red0[t] = p * Wout[t * 2 + 0];
    red1[t] = p * Wout[t * 2 + 1];
    __syncthreads();
    for (int off = F2 / 2; off > 0; off >>= 1) {
        if (t < off) { red0[t] += red0[t + off]; red1[t] += red1[t + off]; }
        __syncthreads();
    }
    if (t == 0) {
        float l0 = red0[0] + bout[0];
        float l1 = red1[0] + bout[1];
        float m = fmaxf(l0, l1);
        float e0 = __expf(l0 - m), e1 = __expf(l1 - m);
        float inv = 1.f / (e0 + e1);
        out[g * 2 + 0] = e0 * inv;
        out[g * 2 + 1] = e1 * inv;
    }
}

extern "C" void kernel_launch(void* const* d_in, const int* in_sizes, int n_in,
                              void* d_out, int out_size, void* d_ws, size_t ws_size,
                              hipStream_t stream) {
    const float* x     = (const float*)d_in[0];
    const int*   ei    = (const int*)d_in[1];
    const int*   batch = (const int*)d_in[2];
    const float* W1    = (const float*)d_in[3];
    const float* asrc1 = (const float*)d_in[4];
    const float* adst1 = (const float*)d_in[5];
    const float* b1    = (const float*)d_in[6];
    const float* W2    = (const float*)d_in[7];
    const float* asrc2 = (const float*)d_in[8];
    const float* adst2 = (const float*)d_in[9];
    const float* b2    = (const float*)d_in[10];
    const float* Wout  = (const float*)d_in[11];
    const float* bout  = (const float*)d_in[12];

    char* ws = (char*)d_ws;
    size_t off = 0;
    auto alloc = [&](size_t bytes) -> void* {
        void* p = ws + off;
        off += (bytes + 255) / 256 * 256;
        return p;
    };
    ushortT* u_h   = (ushortT*)alloc(sizeof(ushortT) * (size_t)N_NODES * F1);
    ushortT* u_x1  = (ushortT*)alloc(sizeof(ushortT) * (size_t)N_NODES * F1);
    float*   f_x2  = (float*)alloc(sizeof(float) * (size_t)N_NODES * F2);
    float*   f_s   = (float*)alloc(sizeof(float) * (size_t)N_NODES * HEADS);
    float*   f_d   = (float*)alloc(sizeof(float) * (size_t)N_NODES * HEADS);
    int*     i_cnt = (int*)alloc(sizeof(int) * (size_t)N_NODES);
    int*     i_off = (int*)alloc(sizeof(int) * (size_t)(N_NODES + 1));
    int*     i_cur = (int*)alloc(sizeof(int) * (size_t)N_NODES);
    int*     i_csr = (int*)alloc(sizeof(int) * (size_t)ETOT);
    int*     i_bnd = (int*)alloc(sizeof(int) * (size_t)(N_GRAPHS + 1));
    int*     i_bs  = (int*)alloc(sizeof(int) * SCAN_NB);
    int*     i_bb  = (int*)alloc(sizeof(int) * SCAN_NB);
    float*   f_prt = (float*)alloc(sizeof(float) * (size_t)N_GRAPHS * POOL_SPLITS * F2);
    ushortT* pW1   = (ushortT*)alloc(sizeof(ushortT) * IN_CH * F1);
    ushortT* pW2   = (ushortT*)alloc(sizeof(ushortT) * F1 * F2);
    (void)ws_size; (void)in_sizes; (void)n_in; (void)out_size;

    hipMemsetAsync(i_cnt, 0, sizeof(int) * N_NODES, stream);
    hipMemsetAsync(i_cur, 0, sizeof(int) * N_NODES, stream);

    // CSR over dst (same for both layers); 3-phase parallel exclusive scan
    k_count<<<(ETOT + 255) / 256, 256, 0, stream>>>(ei, i_cnt);
    k_scan1<<<SCAN_NB, SCAN_B, 0, stream>>>(i_cnt, i_off, i_bs);
    k_scan2<<<1, SCAN_B, 0, stream>>>(i_bs, i_bb, i_off);
    k_scan3<<<SCAN_NB, SCAN_B, 0, stream>>>(i_off, i_bb);
    k_scatter<<<(ETOT + 255) / 256, 256, 0, stream>>>(ei, i_off, i_cur, i_csr);

    // Pack weights into MFMA B-fragment order (bf16)
    k_packW<IN_CH, F1><<<(IN_CH * F1 / 8 + 255) / 256, 256, 0, stream>>>(W1, pW1);
    k_packW<F1, F2><<<(F1 * F2 / 8 + 255) / 256, 256, 0, stream>>>(W2, pW2);

    int gemm_grid = (N_NODES + 63) / 64;
    int agg_grid = (N_NODES / 2 + 3) / 4;  // 2 nodes per wave, 4 waves per block

    // Layer 1
    k_gemm_mfma<IN_CH, F1, false><<<gemm_grid, 256, 0, stream>>>(x, (const uint4*)pW1, u_h, N_NODES);
    k_sd<HEADS, HID><<<(N_NODES * HEADS + 255) / 256, 256, 0, stream>>>(u_h, asrc1, adst1, f_s, f_d);
    k_agg<HEADS, HID, 4, true, 4, 64><<<agg_grid, 256, 0, stream>>>(u_h, f_s, f_d, i_off, i_csr, b1, u_x1);

    // Layer 2
    k_gemm_mfma<F1, F2, true><<<gemm_grid, 256, 0, stream>>>(u_x1, (const uint4*)pW2, u_h, N_NODES);
    k_sd<HEADS, OUT_CH><<<(N_NODES * HEADS + 255) / 256, 256, 0, stream>>>(u_h, asrc2, adst2, f_s, f_d);
    k_agg<HEADS, OUT_CH, 2, false, 4, 64><<<agg_grid, 256, 0, stream>>>(u_h, f_s, f_d, i_off, i_csr, b2, f_x2);

    // Pool + head (no atomics: batch is sorted -> contiguous graph ranges)
    k_bounds<<<1, N_GRAPHS + 1, 0, stream>>>(batch, i_bnd);
    dim3 pgrid(N_GRAPHS, POOL_SPLITS);
    k_pool_partial<<<pgrid, F2, 0, stream>>>(f_x2, i_bnd, f_prt);
    k_head<<<N_GRAPHS, F2, 0, stream>>>(f_prt, i_bnd, Wout, bout, (float*)d_out);
}

// Round 11
// 380.922 us; speedup vs baseline: 1.0050x; 1.0050x over previous
//
#include <hip/hip_runtime.h>
#include <hip/hip_bf16.h>

#define N_NODES 50000
#define N_EDGES 800000
#define ETOT (N_EDGES + N_NODES)
#define N_GRAPHS 64
#define HEADS 4
#define IN_CH 128
#define HID 64
#define F1 256  // HEADS*HID
#define OUT_CH 32
#define F2 128  // HEADS*OUT_CH
#define POOL_SPLITS 16
#define SCAN_B 256
#define SCAN_NB ((N_NODES + SCAN_B - 1) / SCAN_B)  // 196

typedef unsigned short ushortT;
typedef unsigned int uintT;
typedef short v8s __attribute__((ext_vector_type(8)));
typedef float v4f __attribute__((ext_vector_type(4)));

__device__ __forceinline__ ushortT f2bf(float f) {
    union { float f; unsigned int i; } v; v.f = f;
    unsigned int x = v.i;
    unsigned int r = (x + 0x7fffu + ((x >> 16) & 1u)) >> 16;  // RNE
    return (ushortT)r;
}
__device__ __forceinline__ float bf_lo(uintT w) {
    union { unsigned int i; float f; } v; v.i = w << 16; return v.f;
}
__device__ __forceinline__ float bf_hi(uintT w) {
    union { unsigned int i; float f; } v; v.i = w & 0xffff0000u; return v.f;
}

// ---- CSR build over dst (shared by both GAT layers) ----
__global__ void k_count(const int* __restrict__ ei, int* __restrict__ counts) {
    int e = blockIdx.x * blockDim.x + threadIdx.x;
    if (e >= ETOT) return;
    int dst = (e < N_EDGES) ? ei[N_EDGES + e] : (e - N_EDGES);
    atomicAdd(&counts[dst], 1);
}

// ---- parallel 3-phase exclusive scan ----
__global__ void k_scan1(const int* __restrict__ counts, int* __restrict__ offs,
                        int* __restrict__ bsum) {
    __shared__ int sh[SCAN_B];
    int b = blockIdx.x, t = threadIdx.x;
    int i = b * SCAN_B + t;
    int v = (i < N_NODES) ? counts[i] : 0;
    sh[t] = v;
    __syncthreads();
    for (int o = 1; o < SCAN_B; o <<= 1) {
        int add = (t >= o) ? sh[t - o] : 0;
        __syncthreads();
        sh[t] += add;
        __syncthreads();
    }
    if (i < N_NODES) offs[i] = sh[t] - v;
    if (t == SCAN_B - 1) bsum[b] = sh[t];
}

__global__ void k_scan2(const int* __restrict__ bsum, int* __restrict__ bbase,
                        int* __restrict__ offs) {
    __shared__ int sh[SCAN_B];
    int t = threadIdx.x;
    int v = (t < SCAN_NB) ? bsum[t] : 0;
    sh[t] = v;
    __syncthreads();
    for (int o = 1; o < SCAN_B; o <<= 1) {
        int add = (t >= o) ? sh[t - o] : 0;
        __syncthreads();
        sh[t] += add;
        __syncthreads();
    }
    if (t < SCAN_NB) bbase[t] = sh[t] - v;
    if (t == SCAN_B - 1) offs[N_NODES] = sh[t];
}

__global__ void k_scan3(int* __restrict__ offs, const int* __restrict__ bbase) {
    int i = blockIdx.x * SCAN_B + threadIdx.x;
    if (i < N_NODES) offs[i] += bbase[blockIdx.x];
}

__global__ void k_scatter(const int* __restrict__ ei, const int* __restrict__ offsets,
                          int* __restrict__ cursor, int* __restrict__ csr_src) {
    int e = blockIdx.x * blockDim.x + threadIdx.x;
    if (e >= ETOT) return;
    int src, dst;
    if (e < N_EDGES) { src = ei[e]; dst = ei[N_EDGES + e]; }
    else             { src = dst = e - N_EDGES; }
    int pos = offsets[dst] + atomicAdd(&cursor[dst], 1);
    csr_src[pos] = src;
}

// ---- pack W (fp32 [K][N]) into bf16 B-fragment order for 16x16x32 MFMA ----
template <int FIN, int FOUT>
__global__ void k_packW(const float* __restrict__ W, ushortT* __restrict__ pW) {
    constexpr int KC = FIN / 32;
    int tid = blockIdx.x * blockDim.x + threadIdx.x;
    if (tid >= FIN * FOUT / 8) return;
    int lane = tid & 63;
    int g = tid >> 6;
    int kc = g % KC, nt = g / KC;
    int n = nt * 16 + (lane & 15);
    int kbase = kc * 32 + (lane >> 4) * 8;
    union { uint4 q; ushortT u[8]; } pk;
#pragma unroll
    for (int j = 0; j < 8; j++) pk.u[j] = f2bf(W[(kbase + j) * FOUT + n]);
    ((uint4*)pW)[tid] = pk.q;
}

// ---- MFMA GEMM: out[r][n] = sum_k A[r][k]*W[k][n], bf16 out ----
// No LDS, no barriers: B-fragments streamed straight from L2 (W is tiny and
// shared by all blocks); occupancy VGPR-bound instead of 64KB-LDS-bound.
template <int FIN, int FOUT, bool ABF16>
__global__ __launch_bounds__(256) void k_gemm_mfma(const void* __restrict__ A,
                                                   const uint4* __restrict__ Wp,
                                                   ushortT* __restrict__ out, int nrows) {
    constexpr int KC = FIN / 32;
    constexpr int NT = FOUT / 16;
    int tid = threadIdx.x;
    int wave = tid >> 6, lane = tid & 63;
    long row0 = (long)blockIdx.x * 64 + wave * 16;
    if (row0 >= nrows) return;  // wave-uniform (nrows % 16 == 0)
    int m = lane & 15, b = lane >> 4;

    v8s afrag[KC];
    if (ABF16) {
        const ushortT* Ab = (const ushortT*)A;
#pragma unroll
        for (int kc = 0; kc < KC; kc++) {
            union { v8s v; uint4 q; } u;
            u.q = *(const uint4*)(Ab + (row0 + m) * FIN + kc * 32 + b * 8);
            afrag[kc] = u.v;
        }
    } else {
        const float* Af = (const float*)A;
#pragma unroll
        for (int kc = 0; kc < KC; kc++) {
            union { v8s v; ushortT u[8]; } u;
            const float* p = Af + (row0 + m) * FIN + kc * 32 + b * 8;
#pragma unroll
            for (int j = 0; j < 8; j++) u.u[j] = f2bf(p[j]);
            afrag[kc] = u.v;
        }
    }

#pragma unroll
    for (int nt = 0; nt < NT; nt++) {
        v4f c = {0.f, 0.f, 0.f, 0.f};
#pragma unroll
        for (int kc = 0; kc < KC; kc++) {
            union { v8s v; uint4 q; } bu;
            bu.q = Wp[(nt * KC + kc) * 64 + lane];
            c = __builtin_amdgcn_mfma_f32_16x16x32_bf16(afrag[kc], bu.v, c, 0, 0, 0);
        }
        // C/D: col = lane&15, row = (lane>>4)*4 + reg   [measured m89/m91]
        long r = row0 + b * 4;
        int col = nt * 16 + m;
#pragma unroll
        for (int reg = 0; reg < 4; reg++)
            out[(r + reg) * FOUT + col] = f2bf(c[reg]);
    }
}

// ---- per-node per-head attention terms s,d (bf16 h input) ----
template <int H, int C>
__global__ void k_sd(const ushortT* __restrict__ hb, const float* __restrict__ asrc,
                     const float* __restrict__ adst,
                     float* __restrict__ s, float* __restrict__ d) {
    int tid = blockIdx.x * blockDim.x + threadIdx.x;
    if (tid >= N_NODES * H) return;
    int n = tid / H, h = tid - n * H;
    const uintT* row = (const uintT*)(hb + (long)n * (H * C) + h * C);
    float ss = 0.f, dd = 0.f;
#pragma unroll 4
    for (int c2 = 0; c2 < C / 2; c2++) {
        uintT w = row[c2];
        float v0 = bf_lo(w), v1 = bf_hi(w);
        ss += v0 * asrc[h * C + 2 * c2] + v1 * asrc[h * C + 2 * c2 + 1];
        dd += v0 * adst[h * C + 2 * c2] + v1 * adst[h * C + 2 * c2 + 1];
    }
    s[tid] = ss; d[tid] = dd;
}

// ---- fused segment-softmax + aggregation: one node/wave, dual-edge halves ----
// r9 structure (private LDS slice per wave, no barriers, CHUNK=128 staging)
// with the gather reorganized: lanes 0-31 take even edges, lanes 32-63 odd
// edges, each lane loading 16B/8B -> one VMEM instruction covers TWO 512B/256B
// rows (1KB coalescing sweet spot, 2x independent requests, VGPR state
// unchanged). Half-wave partials merge via __shfl_xor(...,32) at the end.
// exp once per (edge,head); no max pass (|e| <~ 6: fp32-safe).
template <int H, int C, bool OUT_BF16, int WPB, int CHUNK>
__global__ __launch_bounds__(64 * WPB) void k_agg(
        const ushortT* __restrict__ hb, const float* __restrict__ s,
        const float* __restrict__ d, const int* __restrict__ offsets,
        const int* __restrict__ csr_src, const float* __restrict__ bias,
        void* __restrict__ xout) {
    static_assert(H == 4, "H=4 assumed");
    constexpr int F = H * C;
    constexpr int FPL = F / 32;          // features per lane (8 for F1, 4 for F2)
    __shared__ int   lsrc[WPB][CHUNK];
    __shared__ float lex[WPB][CHUNK * H];
    int wv = threadIdx.x >> 6;
    int n = blockIdx.x * WPB + wv;
    if (n >= N_NODES) return;
    int t = threadIdx.x & 63;
    int lt = t & 31;                     // lane within half
    int half = t >> 5;                   // 0: even edges, 1: odd edges
    int h = (lt * FPL) / C;              // head of this lane's features (= lt>>3)
    int beg = offsets[n], end = offsets[n + 1];
    float4 dn = *(const float4*)(d + n * 4);

    float sumex = 0.f;
    float acc[FPL];
#pragma unroll
    for (int j = 0; j < FPL; j++) acc[j] = 0.f;

    const uint4* hb4 = (const uint4*)hb;  // 8 bf16 per uint4, 32/lane-row
    const uint2* hb2 = (const uint2*)hb;  // 4 bf16 per uint2

    for (int base = beg; base < end; base += CHUNK) {
        int cnt = min(CHUNK, end - base);
        // phase 1: stage src ids + per-head exp into this wave's LDS slice
        for (int i = t; i < cnt; i += 64) {
            int sn = csr_src[base + i];
            lsrc[wv][i] = sn;
            float4 sv = *(const float4*)(s + sn * 4);
            float e0 = sv.x + dn.x; e0 = e0 > 0.f ? e0 : 0.2f * e0;
            float e1 = sv.y + dn.y; e1 = e1 > 0.f ? e1 : 0.2f * e1;
            float e2 = sv.z + dn.z; e2 = e2 > 0.f ? e2 : 0.2f * e2;
            float e3 = sv.w + dn.w; e3 = e3 > 0.f ? e3 : 0.2f * e3;
            float4 exv = { __expf(e0), __expf(e1), __expf(e2), __expf(e3) };
            *(float4*)&lex[wv][i * 4] = exv;
        }
        // intra-wave LDS write->read ordering (no block barrier needed)
        asm volatile("s_waitcnt lgkmcnt(0)" ::: "memory");
        // phase 2: accumulate, 2 edges per iteration (one per half-wave)
#pragma unroll 4
        for (int i = 0; i < cnt; i += 2) {
            int e = i + half;
            if (e < cnt) {
                float ex = lex[wv][e * H + h];
                int sn = lsrc[wv][e];
                sumex += ex;
                if (FPL == 8) {
                    uint4 w = hb4[(long)sn * 32 + lt];
                    acc[0] += ex * bf_lo(w.x); acc[1] += ex * bf_hi(w.x);
                    acc[2] += ex * bf_lo(w.y); acc[3] += ex * bf_hi(w.y);
                    acc[4] += ex * bf_lo(w.z); acc[5] += ex * bf_hi(w.z);
                    acc[6] += ex * bf_lo(w.w); acc[7] += ex * bf_hi(w.w);
                } else {
                    uint2 w = hb2[(long)sn * 32 + lt];
                    acc[0] += ex * bf_lo(w.x); acc[1] += ex * bf_hi(w.x);
                    acc[2] += ex * bf_lo(w.y); acc[3] += ex * bf_hi(w.y);
                }
            }
        }
        asm volatile("" ::: "memory");
    }
    // merge the two half-wave partials (both halves hold the same features)
    sumex += __shfl_xor(sumex, 32);
#pragma unroll
    for (int j = 0; j < FPL; j++) acc[j] += __shfl_xor(acc[j], 32);

    float inv = 1.f / (sumex + 1e-16f);
    float o[FPL];
#pragma unroll
    for (int j = 0; j < FPL; j++)
        o[j] = fmaxf(acc[j] * inv + bias[lt * FPL + j], 0.f);

    if (half == 0) {  // lanes 0-31 write the full row
        if (OUT_BF16) {
            uint4 pk;
            pk.x = (uintT)f2bf(o[0]) | ((uintT)f2bf(o[1]) << 16);
            pk.y = (uintT)f2bf(o[2]) | ((uintT)f2bf(o[3]) << 16);
            if (FPL == 8) {
                pk.z = (uintT)f2bf(o[4]) | ((uintT)f2bf(o[5]) << 16);
                pk.w = (uintT)f2bf(o[6]) | ((uintT)f2bf(o[7]) << 16);
                ((uint4*)xout)[(long)n * 32 + lt] = pk;
            } else {
                uint2 p2 = { pk.x, pk.y };
                ((uint2*)xout)[(long)n * 32 + lt] = p2;
            }
        } else {
            if (FPL == 4) {
                float4 p4 = { o[0], o[1], o[2], o[3] };
                ((float4*)xout)[(long)n * 32 + lt] = p4;
            } else {
                float* xo = (float*)xout;
#pragma unroll
                for (int j = 0; j < FPL; j++) xo[(long)n * F + lt * FPL + j] = o[j];
            }
        }
    }
}

// ---- graph boundaries via binary search on sorted batch ----
__global__ void k_bounds(const int* __restrict__ batch, int* __restrict__ bounds) {
    int g = threadIdx.x;
    if (g > N_GRAPHS) return;
    int lo = 0, hi = N_NODES;
    while (lo < hi) {
        int mid = (lo + hi) >> 1;
        if (batch[mid] < g) lo = mid + 1; else hi = mid;
    }
    bounds[g] = lo;
}

// ---- pool partials: block (g,s) sums a contiguous node slice, no atomics ----
__global__ void k_pool_partial(const float* __restrict__ x3, const int* __restrict__ bounds,
                               float* __restrict__ partial) {
    int g = blockIdx.x, s = blockIdx.y;
    int t = threadIdx.x;
    int n0 = bounds[g], n1 = bounds[g + 1];
    int len = n1 - n0;
    int a = n0 + (int)((long)len * s / POOL_SPLITS);
    int b = n0 + (int)((long)len * (s + 1) / POOL_SPLITS);
    float acc = 0.f;
    for (int n = a; n < b; n++) acc += x3[(long)n * F2 + t];
    partial[((long)g * POOL_SPLITS + s) * F2 + t] = acc;
}

// ---- head: block per graph — reduce partials, mean, logits, softmax ----
__global__ void k_head(const float* __restrict__ partial, const int* __restrict__ bounds,
                       const float* __restrict__ Wout, const float* __restrict__ bout,
                       float* __restrict__ out) {
    __shared__ float red0[F2], red1[F2];
    int g = blockIdx.x;
    int t = threadIdx.x;
    int cntN = bounds[g + 1] - bounds[g];
    float cnt = fmaxf((float)cntN, 1.0f);
    float sum = 0.f;
    for (int s = 0; s < POOL_SPLITS; s++)
        sum += partial[((long)g * POOL_SPLITS + s) * F2 + t];
    float p = sum / cnt;
    red0[t] = p * Wout[t * 2 + 0];
    red1[t] = p * Wout[t * 2 + 1];
    __syncthreads();
    for (int off = F2 / 2; off > 0; off >>= 1) {
        if (t < off) { red0[t] += red0[t + off]; red1[t] += red1[t + off]; }
        __syncthreads();
    }
    if (t == 0) {
        float l0 = red0[0] + bout[0];
        float l1 = red1[0] + bout[1];
        float m = fmaxf(l0, l1);
        float e0 = __expf(l0 - m), e1 = __expf(l1 - m);
        float inv = 1.f / (e0 + e1);
        out[g * 2 + 0] = e0 * inv;
        out[g * 2 + 1] = e1 * inv;
    }
}

extern "C" void kernel_launch(void* const* d_in, const int* in_sizes, int n_in,
                              void* d_out, int out_size, void* d_ws, size_t ws_size,
                              hipStream_t stream) {
    const float* x     = (const float*)d_in[0];
    const int*   ei    = (const int*)d_in[1];
    const int*   batch = (const int*)d_in[2];
    const float* W1    = (const float*)d_in[3];
    const float* asrc1 = (const float*)d_in[4];
    const float* adst1 = (const float*)d_in[5];
    const float* b1    = (const float*)d_in[6];
    const float* W2    = (const float*)d_in[7];
    const float* asrc2 = (const float*)d_in[8];
    const float* adst2 = (const float*)d_in[9];
    const float* b2    = (const float*)d_in[10];
    const float* Wout  = (const float*)d_in[11];
    const float* bout  = (const float*)d_in[12];

    char* ws = (char*)d_ws;
    size_t off = 0;
    auto alloc = [&](size_t bytes) -> void* {
        void* p = ws + off;
        off += (bytes + 255) / 256 * 256;
        return p;
    };
    ushortT* u_h   = (ushortT*)alloc(sizeof(ushortT) * (size_t)N_NODES * F1);
    ushortT* u_x1  = (ushortT*)alloc(sizeof(ushortT) * (size_t)N_NODES * F1);
    float*   f_x2  = (float*)alloc(sizeof(float) * (size_t)N_NODES * F2);
    float*   f_s   = (float*)alloc(sizeof(float) * (size_t)N_NODES * HEADS);
    float*   f_d   = (float*)alloc(sizeof(float) * (size_t)N_NODES * HEADS);
    int*     i_cnt = (int*)alloc(sizeof(int) * (size_t)N_NODES);
    int*     i_off = (int*)alloc(sizeof(int) * (size_t)(N_NODES + 1));
    int*     i_cur = (int*)alloc(sizeof(int) * (size_t)N_NODES);
    int*     i_csr = (int*)alloc(sizeof(int) * (size_t)ETOT);
    int*     i_bnd = (int*)alloc(sizeof(int) * (size_t)(N_GRAPHS + 1));
    int*     i_bs  = (int*)alloc(sizeof(int) * SCAN_NB);
    int*     i_bb  = (int*)alloc(sizeof(int) * SCAN_NB);
    float*   f_prt = (float*)alloc(sizeof(float) * (size_t)N_GRAPHS * POOL_SPLITS * F2);
    ushortT* pW1   = (ushortT*)alloc(sizeof(ushortT) * IN_CH * F1);
    ushortT* pW2   = (ushortT*)alloc(sizeof(ushortT) * F1 * F2);
    (void)ws_size; (void)in_sizes; (void)n_in; (void)out_size;

    hipMemsetAsync(i_cnt, 0, sizeof(int) * N_NODES, stream);
    hipMemsetAsync(i_cur, 0, sizeof(int) * N_NODES, stream);

    // CSR over dst (same for both layers); 3-phase parallel exclusive scan
    k_count<<<(ETOT + 255) / 256, 256, 0, stream>>>(ei, i_cnt);
    k_scan1<<<SCAN_NB, SCAN_B, 0, stream>>>(i_cnt, i_off, i_bs);
    k_scan2<<<1, SCAN_B, 0, stream>>>(i_bs, i_bb, i_off);
    k_scan3<<<SCAN_NB, SCAN_B, 0, stream>>>(i_off, i_bb);
    k_scatter<<<(ETOT + 255) / 256, 256, 0, stream>>>(ei, i_off, i_cur, i_csr);

    // Pack weights into MFMA B-fragment order (bf16)
    k_packW<IN_CH, F1><<<(IN_CH * F1 / 8 + 255) / 256, 256, 0, stream>>>(W1, pW1);
    k_packW<F1, F2><<<(F1 * F2 / 8 + 255) / 256, 256, 0, stream>>>(W2, pW2);

    int gemm_grid = (N_NODES + 63) / 64;
    int agg_grid = (N_NODES + 3) / 4;  // 1 node per wave, 4 waves per block

    // Layer 1
    k_gemm_mfma<IN_CH, F1, false><<<gemm_grid, 256, 0, stream>>>(x, (const uint4*)pW1, u_h, N_NODES);
    k_sd<HEADS, HID><<<(N_NODES * HEADS + 255) / 256, 256, 0, stream>>>(u_h, asrc1, adst1, f_s, f_d);
    k_agg<HEADS, HID, true, 4, 128><<<agg_grid, 256, 0, stream>>>(u_h, f_s, f_d, i_off, i_csr, b1, u_x1);

    // Layer 2
    k_gemm_mfma<F1, F2, true><<<gemm_grid, 256, 0, stream>>>(u_x1, (const uint4*)pW2, u_h, N_NODES);
    k_sd<HEADS, OUT_CH><<<(N_NODES * HEADS + 255) / 256, 256, 0, stream>>>(u_h, asrc2, adst2, f_s, f_d);
    k_agg<HEADS, OUT_CH, false, 4, 128><<<agg_grid, 256, 0, stream>>>(u_h, f_s, f_d, i_off, i_csr, b2, f_x2);

    // Pool + head (no atomics: batch is sorted -> contiguous graph ranges)
    k_bounds<<<1, N_GRAPHS + 1, 0, stream>>>(batch, i_bnd);
    dim3 pgrid(N_GRAPHS, POOL_SPLITS);
    k_pool_partial<<<pgrid, F2, 0, stream>>>(f_x2, i_bnd, f_prt);
    k_head<<<N_GRAPHS, F2, 0, stream>>>(f_prt, i_bnd, Wout, bout, (float*)d_out);
}

// Round 12
// 353.932 us; speedup vs baseline: 1.0817x; 1.0763x over previous
//
#include <hip/hip_runtime.h>
#include <hip/hip_bf16.h>

#define N_NODES 50000
#define N_EDGES 800000
#define ETOT (N_EDGES + N_NODES)
#define N_GRAPHS 64
#define HEADS 4
#define IN_CH 128
#define HID 64
#define F1 256  // HEADS*HID
#define OUT_CH 32
#define F2 128  // HEADS*OUT_CH
#define POOL_SPLITS 16
#define SCAN_B 256
#define SCAN_NB ((N_NODES + SCAN_B - 1) / SCAN_B)  // 196

typedef unsigned short ushortT;
typedef unsigned int uintT;
typedef short v8s __attribute__((ext_vector_type(8)));
typedef float v4f __attribute__((ext_vector_type(4)));

__device__ __forceinline__ ushortT f2bf(float f) {
    union { float f; unsigned int i; } v; v.f = f;
    unsigned int x = v.i;
    unsigned int r = (x + 0x7fffu + ((x >> 16) & 1u)) >> 16;  // RNE
    return (ushortT)r;
}
__device__ __forceinline__ float bf_lo(uintT w) {
    union { unsigned int i; float f; } v; v.i = w << 16; return v.f;
}
__device__ __forceinline__ float bf_hi(uintT w) {
    union { unsigned int i; float f; } v; v.i = w & 0xffff0000u; return v.f;
}

// ---- CSR build over dst (shared by both GAT layers) ----
__global__ void k_count(const int* __restrict__ ei, int* __restrict__ counts) {
    int e = blockIdx.x * blockDim.x + threadIdx.x;
    if (e >= ETOT) return;
    int dst = (e < N_EDGES) ? ei[N_EDGES + e] : (e - N_EDGES);
    atomicAdd(&counts[dst], 1);
}

// ---- parallel 3-phase exclusive scan ----
__global__ void k_scan1(const int* __restrict__ counts, int* __restrict__ offs,
                        int* __restrict__ bsum) {
    __shared__ int sh[SCAN_B];
    int b = blockIdx.x, t = threadIdx.x;
    int i = b * SCAN_B + t;
    int v = (i < N_NODES) ? counts[i] : 0;
    sh[t] = v;
    __syncthreads();
    for (int o = 1; o < SCAN_B; o <<= 1) {
        int add = (t >= o) ? sh[t - o] : 0;
        __syncthreads();
        sh[t] += add;
        __syncthreads();
    }
    if (i < N_NODES) offs[i] = sh[t] - v;
    if (t == SCAN_B - 1) bsum[b] = sh[t];
}

__global__ void k_scan2(const int* __restrict__ bsum, int* __restrict__ bbase,
                        int* __restrict__ offs) {
    __shared__ int sh[SCAN_B];
    int t = threadIdx.x;
    int v = (t < SCAN_NB) ? bsum[t] : 0;
    sh[t] = v;
    __syncthreads();
    for (int o = 1; o < SCAN_B; o <<= 1) {
        int add = (t >= o) ? sh[t - o] : 0;
        __syncthreads();
        sh[t] += add;
        __syncthreads();
    }
    if (t < SCAN_NB) bbase[t] = sh[t] - v;
    if (t == SCAN_B - 1) offs[N_NODES] = sh[t];
}

__global__ void k_scan3(int* __restrict__ offs, const int* __restrict__ bbase) {
    int i = blockIdx.x * SCAN_B + threadIdx.x;
    if (i < N_NODES) offs[i] += bbase[blockIdx.x];
}

__global__ void k_scatter(const int* __restrict__ ei, const int* __restrict__ offsets,
                          int* __restrict__ cursor, int* __restrict__ csr_src) {
    int e = blockIdx.x * blockDim.x + threadIdx.x;
    if (e >= ETOT) return;
    int src, dst;
    if (e < N_EDGES) { src = ei[e]; dst = ei[N_EDGES + e]; }
    else             { src = dst = e - N_EDGES; }
    int pos = offsets[dst] + atomicAdd(&cursor[dst], 1);
    csr_src[pos] = src;
}

// ---- pack W (fp32 [K][N]) into bf16 B-fragment order for 16x16x32 MFMA ----
template <int FIN, int FOUT>
__global__ void k_packW(const float* __restrict__ W, ushortT* __restrict__ pW) {
    constexpr int KC = FIN / 32;
    int tid = blockIdx.x * blockDim.x + threadIdx.x;
    if (tid >= FIN * FOUT / 8) return;
    int lane = tid & 63;
    int g = tid >> 6;
    int kc = g % KC, nt = g / KC;
    int n = nt * 16 + (lane & 15);
    int kbase = kc * 32 + (lane >> 4) * 8;
    union { uint4 q; ushortT u[8]; } pk;
#pragma unroll
    for (int j = 0; j < 8; j++) pk.u[j] = f2bf(W[(kbase + j) * FOUT + n]);
    ((uint4*)pW)[tid] = pk.q;
}

// ---- MFMA GEMM + fused s,d epilogue ----
// LDS-staged W (measured best, r8); per nt-tile each lane also accumulates
// c[reg]*asrc/adst for its col; at head boundaries a 4-step shfl_xor butterfly
// over the 16 m-lanes produces s[row][head], d[row][head] (replaces k_sd).
template <int FIN, int FOUT, bool ABF16>
__global__ __launch_bounds__(256) void k_gemm_mfma(const void* __restrict__ A,
                                                   const uint4* __restrict__ Wp,
                                                   const float* __restrict__ ASrc,
                                                   const float* __restrict__ ADst,
                                                   ushortT* __restrict__ out,
                                                   float* __restrict__ s_out_g,
                                                   float* __restrict__ d_out_g,
                                                   int nrows) {
    constexpr int KC = FIN / 32;
    constexpr int NT = FOUT / 16;
    constexpr int C = FOUT / HEADS;       // per-head channels
    constexpr int NTH = C / 16;           // nt tiles per head
    __shared__ uintT lW[FIN * FOUT / 2];  // 64 KB
    int tid = threadIdx.x;
    uint4* lW4 = (uint4*)lW;
    for (int i = tid; i < FIN * FOUT * 2 / 16; i += 256) lW4[i] = Wp[i];
    __syncthreads();

    int wave = tid >> 6, lane = tid & 63;
    long row0 = (long)blockIdx.x * 64 + wave * 16;
    if (row0 >= nrows) return;  // wave-uniform (nrows % 16 == 0)
    int m = lane & 15, b = lane >> 4;

    v8s afrag[KC];
    if (ABF16) {
        const ushortT* Ab = (const ushortT*)A;
#pragma unroll
        for (int kc = 0; kc < KC; kc++) {
            union { v8s v; uint4 q; } u;
            u.q = *(const uint4*)(Ab + (row0 + m) * FIN + kc * 32 + b * 8);
            afrag[kc] = u.v;
        }
    } else {
        const float* Af = (const float*)A;
#pragma unroll
        for (int kc = 0; kc < KC; kc++) {
            union { v8s v; ushortT u[8]; } u;
            const float* p = Af + (row0 + m) * FIN + kc * 32 + b * 8;
#pragma unroll
            for (int j = 0; j < 8; j++) u.u[j] = f2bf(p[j]);
            afrag[kc] = u.v;
        }
    }

    float sp[4] = {0.f, 0.f, 0.f, 0.f}, dp[4] = {0.f, 0.f, 0.f, 0.f};
    float s_keep[4], d_keep[4];
    const ushortT* lWs = (const ushortT*)lW;
#pragma unroll
    for (int nt = 0; nt < NT; nt++) {
        v4f c = {0.f, 0.f, 0.f, 0.f};
#pragma unroll
        for (int kc = 0; kc < KC; kc++) {
            union { v8s v; uint4 q; } bu;
            bu.q = *(const uint4*)(lWs + ((nt * KC + kc) * 64 + lane) * 8);
            c = __builtin_amdgcn_mfma_f32_16x16x32_bf16(afrag[kc], bu.v, c, 0, 0, 0);
        }
        // C/D: col = lane&15, row = (lane>>4)*4 + reg   [measured m89/m91]
        long r = row0 + b * 4;
        int col = nt * 16 + m;
#pragma unroll
        for (int reg = 0; reg < 4; reg++)
            out[(r + reg) * FOUT + col] = f2bf(c[reg]);
        // s,d partials for this col
        float av = ASrc[col], dv = ADst[col];
#pragma unroll
        for (int reg = 0; reg < 4; reg++) {
            sp[reg] += c[reg] * av;
            dp[reg] += c[reg] * dv;
        }
        if ((nt % NTH) == NTH - 1) {  // head boundary: reduce over 16 m-lanes
#pragma unroll
            for (int o = 1; o < 16; o <<= 1) {
#pragma unroll
                for (int reg = 0; reg < 4; reg++) {
                    sp[reg] += __shfl_xor(sp[reg], o, 64);
                    dp[reg] += __shfl_xor(dp[reg], o, 64);
                }
            }
            int hd = nt / NTH;
#pragma unroll
            for (int reg = 0; reg < 4; reg++) {
                if (m == hd) { s_keep[reg] = sp[reg]; d_keep[reg] = dp[reg]; }
                sp[reg] = 0.f; dp[reg] = 0.f;
            }
        }
    }
    if (m < HEADS) {
        long r = row0 + b * 4;
#pragma unroll
        for (int reg = 0; reg < 4; reg++) {
            s_out_g[(r + reg) * HEADS + m] = s_keep[reg];
            d_out_g[(r + reg) * HEADS + m] = d_keep[reg];
        }
    }
}

// ---- fused segment-softmax + aggregation: one node per wave, NO barriers ----
// (r9 structure — measured best at 63.3us.) WPB waves/block, private LDS slice
// per wave. Phase 1: lane i stages edge base+i (coalesced csr_src load, float4
// s-gather, 4 exps, b128 LDS write). Intra-wave LDS visibility via s_waitcnt
// lgkmcnt(0) only. Phase 2: broadcast LDS reads + vectorized bf16 gather.
// exp once per (edge,head); no max pass (|e| <~ 6: fp32-safe).
template <int H, int C, int VEC, bool OUT_BF16, int WPB, int CHUNK>
__global__ __launch_bounds__(64 * WPB) void k_agg(
        const ushortT* __restrict__ hb, const float* __restrict__ s,
        const float* __restrict__ d, const int* __restrict__ offsets,
        const int* __restrict__ csr_src, const float* __restrict__ bias,
        void* __restrict__ xout) {
    static_assert(H == 4, "H=4 assumed");
    constexpr int F = H * C;
    constexpr int TPN = F / VEC;
    static_assert(TPN == 64, "one wave per node");
    __shared__ int lsrc[WPB][CHUNK];
    __shared__ float lex[WPB][CHUNK * H];
    int wv = threadIdx.x >> 6;
    int n = blockIdx.x * WPB + wv;
    if (n >= N_NODES) return;
    int t = threadIdx.x & 63;
    int h = t / (C / VEC);
    int beg = offsets[n], end = offsets[n + 1];
    float4 dn = *(const float4*)(d + n * 4);

    float sumex = 0.f;
    float acc[VEC];
#pragma unroll
    for (int j = 0; j < VEC; j++) acc[j] = 0.f;

    const uint2* hb2 = (const uint2*)hb;
    const uintT* hb1 = (const uintT*)hb;

    for (int base = beg; base < end; base += CHUNK) {
        int cnt = min(CHUNK, end - base);
        // phase 1: stage src ids + per-head exp into this wave's LDS slice
        for (int i = t; i < cnt; i += 64) {
            int sn = csr_src[base + i];
            lsrc[wv][i] = sn;
            float4 sv = *(const float4*)(s + sn * 4);
            float e0 = sv.x + dn.x; e0 = e0 > 0.f ? e0 : 0.2f * e0;
            float e1 = sv.y + dn.y; e1 = e1 > 0.f ? e1 : 0.2f * e1;
            float e2 = sv.z + dn.z; e2 = e2 > 0.f ? e2 : 0.2f * e2;
            float e3 = sv.w + dn.w; e3 = e3 > 0.f ? e3 : 0.2f * e3;
            float4 exv = { __expf(e0), __expf(e1), __expf(e2), __expf(e3) };
            *(float4*)&lex[wv][i * 4] = exv;
        }
        // intra-wave LDS write->read ordering (no block barrier needed)
        asm volatile("s_waitcnt lgkmcnt(0)" ::: "memory");
        // phase 2: accumulate
#pragma unroll 4
        for (int i = 0; i < cnt; i++) {
            float ex = lex[wv][i * H + h];
            int sn = lsrc[wv][i];
            sumex += ex;
            if (VEC == 4) {
                uint2 w = hb2[(long)sn * TPN + t];
                acc[0] += ex * bf_lo(w.x);
                acc[1] += ex * bf_hi(w.x);
                acc[2] += ex * bf_lo(w.y);
                acc[3] += ex * bf_hi(w.y);
            } else {
                uintT w = hb1[(long)sn * TPN + t];
                acc[0] += ex * bf_lo(w);
                acc[1] += ex * bf_hi(w);
            }
        }
        asm volatile("" ::: "memory");
    }
    float inv = 1.f / (sumex + 1e-16f);
    float o[VEC];
#pragma unroll
    for (int j = 0; j < VEC; j++)
        o[j] = fmaxf(acc[j] * inv + bias[t * VEC + j], 0.f);
    if (OUT_BF16) {
        if (VEC == 4) {
            uint2 pk;
            pk.x = (uintT)f2bf(o[0]) | ((uintT)f2bf(o[1]) << 16);
            pk.y = (uintT)f2bf(o[2]) | ((uintT)f2bf(o[3]) << 16);
            ((uint2*)xout)[(long)n * TPN + t] = pk;
        } else {
            uintT pk = (uintT)f2bf(o[0]) | ((uintT)f2bf(o[1]) << 16);
            ((uintT*)xout)[(long)n * TPN + t] = pk;
        }
    } else {
        float* xo = (float*)xout;
#pragma unroll
        for (int j = 0; j < VEC; j++) xo[(long)n * F + t * VEC + j] = o[j];
    }
}

// ---- graph boundaries via binary search on sorted batch ----
__global__ void k_bounds(const int* __restrict__ batch, int* __restrict__ bounds) {
    int g = threadIdx.x;
    if (g > N_GRAPHS) return;
    int lo = 0, hi = N_NODES;
    while (lo < hi) {
        int mid = (lo + hi) >> 1;
        if (batch[mid] < g) lo = mid + 1; else hi = mid;
    }
    bounds[g] = lo;
}

// ---- pool partials over bf16 x2: block (g,s) sums a contiguous slice ----
__global__ void k_pool_partial(const ushortT* __restrict__ x2, const int* __restrict__ bounds,
                               float* __restrict__ partial) {
    int g = blockIdx.x, s = blockIdx.y;
    int t = threadIdx.x;  // F2 threads
    int n0 = bounds[g], n1 = bounds[g + 1];
    int len = n1 - n0;
    int a = n0 + (int)((long)len * s / POOL_SPLITS);
    int b = n0 + (int)((long)len * (s + 1) / POOL_SPLITS);
    float acc = 0.f;
    for (int n = a; n < b; n++) acc += bf_lo((uintT)x2[(long)n * F2 + t]);
    partial[((long)g * POOL_SPLITS + s) * F2 + t] = acc;
}

// ---- head: block per graph — reduce partials, mean, logits, softmax ----
__global__ void k_head(const float* __restrict__ partial, const int* __restrict__ bounds,
                       const float* __restrict__ Wout, const float* __restrict__ bout,
                       float* __restrict__ out) {
    __shared__ float red0[F2], red1[F2];
    int g = blockIdx.x;
    int t = threadIdx.x;
    int cntN = bounds[g + 1] - bounds[g];
    float cnt = fmaxf((float)cntN, 1.0f);
    float sum = 0.f;
    for (int s = 0; s < POOL_SPLITS; s++)
        sum += partial[((long)g * POOL_SPLITS + s) * F2 + t];
    float p = sum / cnt;
    red0[t] = p * Wout[t * 2 + 0];
    red1[t] = p * Wout[t * 2 + 1];
    __syncthreads();
    for (int off = F2 / 2; off > 0; off >>= 1) {
        if (t < off) { red0[t] += red0[t + off]; red1[t] += red1[t + off]; }
        __syncthreads();
    }
    if (t == 0) {
        float l0 = red0[0] + bout[0];
        float l1 = red1[0] + bout[1];
        float m = fmaxf(l0, l1);
        float e0 = __expf(l0 - m), e1 = __expf(l1 - m);
        float inv = 1.f / (e0 + e1);
        out[g * 2 + 0] = e0 * inv;
        out[g * 2 + 1] = e1 * inv;
    }
}

extern "C" void kernel_launch(void* const* d_in, const int* in_sizes, int n_in,
                              void* d_out, int out_size, void* d_ws, size_t ws_size,
                              hipStream_t stream) {
    const float* x     = (const float*)d_in[0];
    const int*   ei    = (const int*)d_in[1];
    const int*   batch = (const int*)d_in[2];
    const float* W1    = (const float*)d_in[3];
    const float* asrc1 = (const float*)d_in[4];
    const float* adst1 = (const float*)d_in[5];
    const float* b1    = (const float*)d_in[6];
    const float* W2    = (const float*)d_in[7];
    const float* asrc2 = (const float*)d_in[8];
    const float* adst2 = (const float*)d_in[9];
    const float* b2    = (const float*)d_in[10];
    const float* Wout  = (const float*)d_in[11];
    const float* bout  = (const float*)d_in[12];

    char* ws = (char*)d_ws;
    size_t off = 0;
    auto alloc = [&](size_t bytes) -> void* {
        void* p = ws + off;
        off += (bytes + 255) / 256 * 256;
        return p;
    };
    ushortT* u_h   = (ushortT*)alloc(sizeof(ushortT) * (size_t)N_NODES * F1);
    ushortT* u_x1  = (ushortT*)alloc(sizeof(ushortT) * (size_t)N_NODES * F1);
    ushortT* u_x2  = (ushortT*)alloc(sizeof(ushortT) * (size_t)N_NODES * F2);
    float*   f_s   = (float*)alloc(sizeof(float) * (size_t)N_NODES * HEADS);
    float*   f_d   = (float*)alloc(sizeof(float) * (size_t)N_NODES * HEADS);
    int*     i_cnt = (int*)alloc(sizeof(int) * (size_t)N_NODES);
    int*     i_off = (int*)alloc(sizeof(int) * (size_t)(N_NODES + 1));
    int*     i_cur = (int*)alloc(sizeof(int) * (size_t)N_NODES);
    int*     i_csr = (int*)alloc(sizeof(int) * (size_t)ETOT);
    int*     i_bnd = (int*)alloc(sizeof(int) * (size_t)(N_GRAPHS + 1));
    int*     i_bs  = (int*)alloc(sizeof(int) * SCAN_NB);
    int*     i_bb  = (int*)alloc(sizeof(int) * SCAN_NB);
    float*   f_prt = (float*)alloc(sizeof(float) * (size_t)N_GRAPHS * POOL_SPLITS * F2);
    ushortT* pW1   = (ushortT*)alloc(sizeof(ushortT) * IN_CH * F1);
    ushortT* pW2   = (ushortT*)alloc(sizeof(ushortT) * F1 * F2);
    (void)ws_size; (void)in_sizes; (void)n_in; (void)out_size;

    hipMemsetAsync(i_cnt, 0, sizeof(int) * N_NODES, stream);
    hipMemsetAsync(i_cur, 0, sizeof(int) * N_NODES, stream);

    // CSR over dst (same for both layers); 3-phase parallel exclusive scan
    k_count<<<(ETOT + 255) / 256, 256, 0, stream>>>(ei, i_cnt);
    k_scan1<<<SCAN_NB, SCAN_B, 0, stream>>>(i_cnt, i_off, i_bs);
    k_scan2<<<1, SCAN_B, 0, stream>>>(i_bs, i_bb, i_off);
    k_scan3<<<SCAN_NB, SCAN_B, 0, stream>>>(i_off, i_bb);
    k_scatter<<<(ETOT + 255) / 256, 256, 0, stream>>>(ei, i_off, i_cur, i_csr);

    // Pack weights into MFMA B-fragment order (bf16)
    k_packW<IN_CH, F1><<<(IN_CH * F1 / 8 + 255) / 256, 256, 0, stream>>>(W1, pW1);
    k_packW<F1, F2><<<(F1 * F2 / 8 + 255) / 256, 256, 0, stream>>>(W2, pW2);

    int gemm_grid = (N_NODES + 63) / 64;
    int agg_grid = (N_NODES + 3) / 4;  // 1 node per wave, 4 waves per block

    // Layer 1 (gemm computes h, s, d in one pass)
    k_gemm_mfma<IN_CH, F1, false><<<gemm_grid, 256, 0, stream>>>(
        x, (const uint4*)pW1, asrc1, adst1, u_h, f_s, f_d, N_NODES);
    k_agg<HEADS, HID, 4, true, 4, 128><<<agg_grid, 256, 0, stream>>>(
        u_h, f_s, f_d, i_off, i_csr, b1, u_x1);

    // Layer 2
    k_gemm_mfma<F1, F2, true><<<gemm_grid, 256, 0, stream>>>(
        u_x1, (const uint4*)pW2, asrc2, adst2, u_h, f_s, f_d, N_NODES);
    k_agg<HEADS, OUT_CH, 2, true, 4, 128><<<agg_grid, 256, 0, stream>>>(
        u_h, f_s, f_d, i_off, i_csr, b2, u_x2);

    // Pool + head (no atomics: batch is sorted -> contiguous graph ranges)
    k_bounds<<<1, N_GRAPHS + 1, 0, stream>>>(batch, i_bnd);
    dim3 pgrid(N_GRAPHS, POOL_SPLITS);
    k_pool_partial<<<pgrid, F2, 0, stream>>>(u_x2, i_bnd, f_prt);
    k_head<<<N_GRAPHS, F2, 0, stream>>>(f_prt, i_bnd, Wout, bout, (float*)d_out);
}

// Round 13
// 348.098 us; speedup vs baseline: 1.0998x; 1.0168x over previous
//
#include <hip/hip_runtime.h>
#include <hip/hip_bf16.h>

#define N_NODES 50000
#define N_EDGES 800000
#define ETOT (N_EDGES + N_NODES)
#define N_GRAPHS 64
#define HEADS 4
#define IN_CH 128
#define HID 64
#define F1 256  // HEADS*HID
#define OUT_CH 32
#define F2 128  // HEADS*OUT_CH
#define POOL_SPLITS 16
#define SCAN_B 256
#define SCAN_NB ((N_NODES + SCAN_B - 1) / SCAN_B)  // 196

typedef unsigned short ushortT;
typedef unsigned int uintT;
typedef short v8s __attribute__((ext_vector_type(8)));
typedef float v4f __attribute__((ext_vector_type(4)));

__device__ __forceinline__ ushortT f2bf(float f) {
    union { float f; unsigned int i; } v; v.f = f;
    unsigned int x = v.i;
    unsigned int r = (x + 0x7fffu + ((x >> 16) & 1u)) >> 16;  // RNE
    return (ushortT)r;
}
__device__ __forceinline__ float bf_lo(uintT w) {
    union { unsigned int i; float f; } v; v.i = w << 16; return v.f;
}
__device__ __forceinline__ float bf_hi(uintT w) {
    union { unsigned int i; float f; } v; v.i = w & 0xffff0000u; return v.f;
}

// ---- CSR build over dst (shared by both GAT layers) ----
__global__ void k_count(const int* __restrict__ ei, int* __restrict__ counts) {
    int e = blockIdx.x * blockDim.x + threadIdx.x;
    if (e >= ETOT) return;
    int dst = (e < N_EDGES) ? ei[N_EDGES + e] : (e - N_EDGES);
    atomicAdd(&counts[dst], 1);
}

// ---- parallel 3-phase exclusive scan (+ graph bounds fused into phase 2) ----
__global__ void k_scan1(const int* __restrict__ counts, int* __restrict__ offs,
                        int* __restrict__ bsum) {
    __shared__ int sh[SCAN_B];
    int b = blockIdx.x, t = threadIdx.x;
    int i = b * SCAN_B + t;
    int v = (i < N_NODES) ? counts[i] : 0;
    sh[t] = v;
    __syncthreads();
    for (int o = 1; o < SCAN_B; o <<= 1) {
        int add = (t >= o) ? sh[t - o] : 0;
        __syncthreads();
        sh[t] += add;
        __syncthreads();
    }
    if (i < N_NODES) offs[i] = sh[t] - v;
    if (t == SCAN_B - 1) bsum[b] = sh[t];
}

__global__ void k_scan2(const int* __restrict__ bsum, int* __restrict__ bbase,
                        int* __restrict__ offs, const int* __restrict__ batch,
                        int* __restrict__ bounds) {
    __shared__ int sh[SCAN_B];
    int t = threadIdx.x;
    int v = (t < SCAN_NB) ? bsum[t] : 0;
    sh[t] = v;
    __syncthreads();
    for (int o = 1; o < SCAN_B; o <<= 1) {
        int add = (t >= o) ? sh[t - o] : 0;
        __syncthreads();
        sh[t] += add;
        __syncthreads();
    }
    if (t < SCAN_NB) bbase[t] = sh[t] - v;
    if (t == SCAN_B - 1) offs[N_NODES] = sh[t];
    // fused: graph boundaries via binary search on sorted batch
    if (t <= N_GRAPHS) {
        int lo = 0, hi = N_NODES;
        while (lo < hi) {
            int mid = (lo + hi) >> 1;
            if (batch[mid] < t) lo = mid + 1; else hi = mid;
        }
        bounds[t] = lo;
    }
}

__global__ void k_scan3(int* __restrict__ offs, const int* __restrict__ bbase) {
    int i = blockIdx.x * SCAN_B + threadIdx.x;
    if (i < N_NODES) offs[i] += bbase[blockIdx.x];
}

__global__ void k_scatter(const int* __restrict__ ei, const int* __restrict__ offsets,
                          int* __restrict__ cursor, int* __restrict__ csr_src) {
    int e = blockIdx.x * blockDim.x + threadIdx.x;
    if (e >= ETOT) return;
    int src, dst;
    if (e < N_EDGES) { src = ei[e]; dst = ei[N_EDGES + e]; }
    else             { src = dst = e - N_EDGES; }
    int pos = offsets[dst] + atomicAdd(&cursor[dst], 1);
    csr_src[pos] = src;
}

// ---- pack W (fp32 [K][N]) into bf16 B-fragment order for 16x16x32 MFMA ----
template <int FIN, int FOUT>
__global__ void k_packW(const float* __restrict__ W, ushortT* __restrict__ pW) {
    constexpr int KC = FIN / 32;
    int tid = blockIdx.x * blockDim.x + threadIdx.x;
    if (tid >= FIN * FOUT / 8) return;
    int lane = tid & 63;
    int g = tid >> 6;
    int kc = g % KC, nt = g / KC;
    int n = nt * 16 + (lane & 15);
    int kbase = kc * 32 + (lane >> 4) * 8;
    union { uint4 q; ushortT u[8]; } pk;
#pragma unroll
    for (int j = 0; j < 8; j++) pk.u[j] = f2bf(W[(kbase + j) * FOUT + n]);
    ((uint4*)pW)[tid] = pk.q;
}

// ---- MFMA GEMM + fused s,d epilogue; 2 row-tiles (32 rows) per wave ----
// Each B-fragment ds_read_b128 feeds TWO MFMAs (K-loop was LDS-read-bound at
// 1:1; ds_read_b128 ~12cyc vs MFMA ~4.8cyc). Grid halves -> W-staging traffic
// per output row halves. Occupancy is LDS-bound (64KB -> 2 blocks/CU) so the
// extra VGPRs are free. s,d computed in-epilogue via shfl_xor butterfly.
template <int FIN, int FOUT, bool ABF16>
__global__ __launch_bounds__(256) void k_gemm_mfma(const void* __restrict__ A,
                                                   const uint4* __restrict__ Wp,
                                                   const float* __restrict__ ASrc,
                                                   const float* __restrict__ ADst,
                                                   ushortT* __restrict__ out,
                                                   float* __restrict__ s_out_g,
                                                   float* __restrict__ d_out_g,
                                                   int nrows) {
    constexpr int KC = FIN / 32;
    constexpr int NT = FOUT / 16;
    constexpr int C = FOUT / HEADS;       // per-head channels
    constexpr int NTH = C / 16;           // nt tiles per head
    __shared__ uintT lW[FIN * FOUT / 2];  // 64 KB
    int tid = threadIdx.x;
    uint4* lW4 = (uint4*)lW;
    for (int i = tid; i < FIN * FOUT * 2 / 16; i += 256) lW4[i] = Wp[i];
    __syncthreads();

    int wave = tid >> 6, lane = tid & 63;
    long rowA = (long)blockIdx.x * 128 + wave * 32;
    long rowB = rowA + 16;
    bool doA = rowA < nrows, doB = rowB < nrows;  // wave-uniform (nrows%16==0)
    if (!doA) return;
    int m = lane & 15, b = lane >> 4;

    v8s afA[KC], afB[KC];
    if (ABF16) {
        const ushortT* Ab = (const ushortT*)A;
#pragma unroll
        for (int kc = 0; kc < KC; kc++) {
            union { v8s v; uint4 q; } u;
            u.q = *(const uint4*)(Ab + (rowA + m) * FIN + kc * 32 + b * 8);
            afA[kc] = u.v;
            if (doB) {
                u.q = *(const uint4*)(Ab + (rowB + m) * FIN + kc * 32 + b * 8);
                afB[kc] = u.v;
            }
        }
    } else {
        const float* Af = (const float*)A;
#pragma unroll
        for (int kc = 0; kc < KC; kc++) {
            union { v8s v; ushortT u[8]; } u;
            const float* p = Af + (rowA + m) * FIN + kc * 32 + b * 8;
#pragma unroll
            for (int j = 0; j < 8; j++) u.u[j] = f2bf(p[j]);
            afA[kc] = u.v;
            if (doB) {
                const float* q = Af + (rowB + m) * FIN + kc * 32 + b * 8;
#pragma unroll
                for (int j = 0; j < 8; j++) u.u[j] = f2bf(q[j]);
                afB[kc] = u.v;
            }
        }
    }

    float spA[4] = {0,0,0,0}, dpA[4] = {0,0,0,0};
    float spB[4] = {0,0,0,0}, dpB[4] = {0,0,0,0};
    float skA[4], dkA[4], skB[4], dkB[4];
    const ushortT* lWs = (const ushortT*)lW;
#pragma unroll
    for (int nt = 0; nt < NT; nt++) {
        v4f cA = {0.f, 0.f, 0.f, 0.f}, cB = {0.f, 0.f, 0.f, 0.f};
#pragma unroll
        for (int kc = 0; kc < KC; kc++) {
            union { v8s v; uint4 q; } bu;
            bu.q = *(const uint4*)(lWs + ((nt * KC + kc) * 64 + lane) * 8);
            cA = __builtin_amdgcn_mfma_f32_16x16x32_bf16(afA[kc], bu.v, cA, 0, 0, 0);
            if (doB)
                cB = __builtin_amdgcn_mfma_f32_16x16x32_bf16(afB[kc], bu.v, cB, 0, 0, 0);
        }
        // C/D: col = lane&15, row = (lane>>4)*4 + reg   [measured m89/m91]
        int col = nt * 16 + m;
        float av = ASrc[col], dv = ADst[col];
        long rA = rowA + b * 4;
#pragma unroll
        for (int reg = 0; reg < 4; reg++) {
            out[(rA + reg) * FOUT + col] = f2bf(cA[reg]);
            spA[reg] += cA[reg] * av;
            dpA[reg] += cA[reg] * dv;
        }
        if (doB) {
            long rB = rowB + b * 4;
#pragma unroll
            for (int reg = 0; reg < 4; reg++) {
                out[(rB + reg) * FOUT + col] = f2bf(cB[reg]);
                spB[reg] += cB[reg] * av;
                dpB[reg] += cB[reg] * dv;
            }
        }
        if ((nt % NTH) == NTH - 1) {  // head boundary: reduce over 16 m-lanes
#pragma unroll
            for (int o = 1; o < 16; o <<= 1) {
#pragma unroll
                for (int reg = 0; reg < 4; reg++) {
                    spA[reg] += __shfl_xor(spA[reg], o, 64);
                    dpA[reg] += __shfl_xor(dpA[reg], o, 64);
                    spB[reg] += __shfl_xor(spB[reg], o, 64);
                    dpB[reg] += __shfl_xor(dpB[reg], o, 64);
                }
            }
            int hd = nt / NTH;
#pragma unroll
            for (int reg = 0; reg < 4; reg++) {
                if (m == hd) {
                    skA[reg] = spA[reg]; dkA[reg] = dpA[reg];
                    skB[reg] = spB[reg]; dkB[reg] = dpB[reg];
                }
                spA[reg] = 0.f; dpA[reg] = 0.f;
                spB[reg] = 0.f; dpB[reg] = 0.f;
            }
        }
    }
    if (m < HEADS) {
        long rA = rowA + b * 4;
#pragma unroll
        for (int reg = 0; reg < 4; reg++) {
            s_out_g[(rA + reg) * HEADS + m] = skA[reg];
            d_out_g[(rA + reg) * HEADS + m] = dkA[reg];
        }
        if (doB) {
            long rB = rowB + b * 4;
#pragma unroll
            for (int reg = 0; reg < 4; reg++) {
                s_out_g[(rB + reg) * HEADS + m] = skB[reg];
                d_out_g[(rB + reg) * HEADS + m] = dkB[reg];
            }
        }
    }
}

// ---- fused segment-softmax + aggregation: one node per wave, NO barriers ----
// (r9 structure — measured best; WPB=8 packs more waves per CU, per-wave state
// unchanged.) Phase 1: lane i stages edge base+i (coalesced csr_src load,
// float4 s-gather, 4 exps, b128 LDS write). Intra-wave LDS visibility via
// s_waitcnt lgkmcnt(0) only. Phase 2: broadcast LDS reads + vectorized bf16
// gather. exp once per (edge,head); no max pass (|e| <~ 6: fp32-safe).
template <int H, int C, int VEC, bool OUT_BF16, int WPB, int CHUNK>
__global__ __launch_bounds__(64 * WPB) void k_agg(
        const ushortT* __restrict__ hb, const float* __restrict__ s,
        const float* __restrict__ d, const int* __restrict__ offsets,
        const int* __restrict__ csr_src, const float* __restrict__ bias,
        void* __restrict__ xout) {
    static_assert(H == 4, "H=4 assumed");
    constexpr int F = H * C;
    constexpr int TPN = F / VEC;
    static_assert(TPN == 64, "one wave per node");
    __shared__ int lsrc[WPB][CHUNK];
    __shared__ float lex[WPB][CHUNK * H];
    int wv = threadIdx.x >> 6;
    int n = blockIdx.x * WPB + wv;
    if (n >= N_NODES) return;
    int t = threadIdx.x & 63;
    int h = t / (C / VEC);
    int beg = offsets[n], end = offsets[n + 1];
    float4 dn = *(const float4*)(d + n * 4);

    float sumex = 0.f;
    float acc[VEC];
#pragma unroll
    for (int j = 0; j < VEC; j++) acc[j] = 0.f;

    const uint2* hb2 = (const uint2*)hb;
    const uintT* hb1 = (const uintT*)hb;

    for (int base = beg; base < end; base += CHUNK) {
        int cnt = min(CHUNK, end - base);
        // phase 1: stage src ids + per-head exp into this wave's LDS slice
        for (int i = t; i < cnt; i += 64) {
            int sn = csr_src[base + i];
            lsrc[wv][i] = sn;
            float4 sv = *(const float4*)(s + sn * 4);
            float e0 = sv.x + dn.x; e0 = e0 > 0.f ? e0 : 0.2f * e0;
            float e1 = sv.y + dn.y; e1 = e1 > 0.f ? e1 : 0.2f * e1;
            float e2 = sv.z + dn.z; e2 = e2 > 0.f ? e2 : 0.2f * e2;
            float e3 = sv.w + dn.w; e3 = e3 > 0.f ? e3 : 0.2f * e3;
            float4 exv = { __expf(e0), __expf(e1), __expf(e2), __expf(e3) };
            *(float4*)&lex[wv][i * 4] = exv;
        }
        // intra-wave LDS write->read ordering (no block barrier needed)
        asm volatile("s_waitcnt lgkmcnt(0)" ::: "memory");
        // phase 2: accumulate
#pragma unroll 4
        for (int i = 0; i < cnt; i++) {
            float ex = lex[wv][i * H + h];
            int sn = lsrc[wv][i];
            sumex += ex;
            if (VEC == 4) {
                uint2 w = hb2[(long)sn * TPN + t];
                acc[0] += ex * bf_lo(w.x);
                acc[1] += ex * bf_hi(w.x);
                acc[2] += ex * bf_lo(w.y);
                acc[3] += ex * bf_hi(w.y);
            } else {
                uintT w = hb1[(long)sn * TPN + t];
                acc[0] += ex * bf_lo(w);
                acc[1] += ex * bf_hi(w);
            }
        }
        asm volatile("" ::: "memory");
    }
    float inv = 1.f / (sumex + 1e-16f);
    float o[VEC];
#pragma unroll
    for (int j = 0; j < VEC; j++)
        o[j] = fmaxf(acc[j] * inv + bias[t * VEC + j], 0.f);
    if (OUT_BF16) {
        if (VEC == 4) {
            uint2 pk;
            pk.x = (uintT)f2bf(o[0]) | ((uintT)f2bf(o[1]) << 16);
            pk.y = (uintT)f2bf(o[2]) | ((uintT)f2bf(o[3]) << 16);
            ((uint2*)xout)[(long)n * TPN + t] = pk;
        } else {
            uintT pk = (uintT)f2bf(o[0]) | ((uintT)f2bf(o[1]) << 16);
            ((uintT*)xout)[(long)n * TPN + t] = pk;
        }
    } else {
        float* xo = (float*)xout;
#pragma unroll
        for (int j = 0; j < VEC; j++) xo[(long)n * F + t * VEC + j] = o[j];
    }
}

// ---- pool partials over bf16 x2: block (g,s) sums a contiguous slice ----
__global__ void k_pool_partial(const ushortT* __restrict__ x2, const int* __restrict__ bounds,
                               float* __restrict__ partial) {
    int g = blockIdx.x, s = blockIdx.y;
    int t = threadIdx.x;  // F2 threads
    int n0 = bounds[g], n1 = bounds[g + 1];
    int len = n1 - n0;
    int a = n0 + (int)((long)len * s / POOL_SPLITS);
    int b = n0 + (int)((long)len * (s + 1) / POOL_SPLITS);
    float acc = 0.f;
    for (int n = a; n < b; n++) acc += bf_lo((uintT)x2[(long)n * F2 + t]);
    partial[((long)g * POOL_SPLITS + s) * F2 + t] = acc;
}

// ---- head: block per graph — reduce partials, mean, logits, softmax ----
__global__ void k_head(const float* __restrict__ partial, const int* __restrict__ bounds,
                       const float* __restrict__ Wout, const float* __restrict__ bout,
                       float* __restrict__ out) {
    __shared__ float red0[F2], red1[F2];
    int g = blockIdx.x;
    int t = threadIdx.x;
    int cntN = bounds[g + 1] - bounds[g];
    float cnt = fmaxf((float)cntN, 1.0f);
    float sum = 0.f;
    for (int s = 0; s < POOL_SPLITS; s++)
        sum += partial[((long)g * POOL_SPLITS + s) * F2 + t];
    float p = sum / cnt;
    red0[t] = p * Wout[t * 2 + 0];
    red1[t] = p * Wout[t * 2 + 1];
    __syncthreads();
    for (int off = F2 / 2; off > 0; off >>= 1) {
        if (t < off) { red0[t] += red0[t + off]; red1[t] += red1[t + off]; }
        __syncthreads();
    }
    if (t == 0) {
        float l0 = red0[0] + bout[0];
        float l1 = red1[0] + bout[1];
        float m = fmaxf(l0, l1);
        float e0 = __expf(l0 - m), e1 = __expf(l1 - m);
        float inv = 1.f / (e0 + e1);
        out[g * 2 + 0] = e0 * inv;
        out[g * 2 + 1] = e1 * inv;
    }
}

extern "C" void kernel_launch(void* const* d_in, const int* in_sizes, int n_in,
                              void* d_out, int out_size, void* d_ws, size_t ws_size,
                              hipStream_t stream) {
    const float* x     = (const float*)d_in[0];
    const int*   ei    = (const int*)d_in[1];
    const int*   batch = (const int*)d_in[2];
    const float* W1    = (const float*)d_in[3];
    const float* asrc1 = (const float*)d_in[4];
    const float* adst1 = (const float*)d_in[5];
    const float* b1    = (const float*)d_in[6];
    const float* W2    = (const float*)d_in[7];
    const float* asrc2 = (const float*)d_in[8];
    const float* adst2 = (const float*)d_in[9];
    const float* b2    = (const float*)d_in[10];
    const float* Wout  = (const float*)d_in[11];
    const float* bout  = (const float*)d_in[12];

    char* ws = (char*)d_ws;
    size_t off = 0;
    auto alloc = [&](size_t bytes) -> void* {
        void* p = ws + off;
        off += (bytes + 255) / 256 * 256;
        return p;
    };
    ushortT* u_h   = (ushortT*)alloc(sizeof(ushortT) * (size_t)N_NODES * F1);
    ushortT* u_x1  = (ushortT*)alloc(sizeof(ushortT) * (size_t)N_NODES * F1);
    ushortT* u_x2  = (ushortT*)alloc(sizeof(ushortT) * (size_t)N_NODES * F2);
    float*   f_s   = (float*)alloc(sizeof(float) * (size_t)N_NODES * HEADS);
    float*   f_d   = (float*)alloc(sizeof(float) * (size_t)N_NODES * HEADS);
    int*     i_cnt = (int*)alloc(sizeof(int) * (size_t)N_NODES);   // adjacent to
    int*     i_cur = (int*)alloc(sizeof(int) * (size_t)N_NODES);   // i_cnt: 1 memset
    int*     i_off = (int*)alloc(sizeof(int) * (size_t)(N_NODES + 1));
    int*     i_csr = (int*)alloc(sizeof(int) * (size_t)ETOT);
    int*     i_bnd = (int*)alloc(sizeof(int) * (size_t)(N_GRAPHS + 1));
    int*     i_bs  = (int*)alloc(sizeof(int) * SCAN_NB);
    int*     i_bb  = (int*)alloc(sizeof(int) * SCAN_NB);
    float*   f_prt = (float*)alloc(sizeof(float) * (size_t)N_GRAPHS * POOL_SPLITS * F2);
    ushortT* pW1   = (ushortT*)alloc(sizeof(ushortT) * IN_CH * F1);
    ushortT* pW2   = (ushortT*)alloc(sizeof(ushortT) * F1 * F2);
    (void)ws_size; (void)in_sizes; (void)n_in; (void)out_size;

    // one memset covers i_cnt + pad + i_cur (adjacent allocations)
    hipMemsetAsync(i_cnt, 0, (size_t)((char*)i_cur - (char*)i_cnt) + sizeof(int) * N_NODES, stream);

    // CSR over dst (same for both layers); 3-phase parallel exclusive scan
    k_count<<<(ETOT + 255) / 256, 256, 0, stream>>>(ei, i_cnt);
    k_scan1<<<SCAN_NB, SCAN_B, 0, stream>>>(i_cnt, i_off, i_bs);
    k_scan2<<<1, SCAN_B, 0, stream>>>(i_bs, i_bb, i_off, batch, i_bnd);
    k_scan3<<<SCAN_NB, SCAN_B, 0, stream>>>(i_off, i_bb);
    k_scatter<<<(ETOT + 255) / 256, 256, 0, stream>>>(ei, i_off, i_cur, i_csr);

    // Pack weights into MFMA B-fragment order (bf16)
    k_packW<IN_CH, F1><<<(IN_CH * F1 / 8 + 255) / 256, 256, 0, stream>>>(W1, pW1);
    k_packW<F1, F2><<<(F1 * F2 / 8 + 255) / 256, 256, 0, stream>>>(W2, pW2);

    int gemm_grid = (N_NODES + 127) / 128;  // 32 rows per wave
    int agg_grid = (N_NODES + 7) / 8;       // 1 node per wave, 8 waves per block

    // Layer 1 (gemm computes h, s, d in one pass)
    k_gemm_mfma<IN_CH, F1, false><<<gemm_grid, 256, 0, stream>>>(
        x, (const uint4*)pW1, asrc1, adst1, u_h, f_s, f_d, N_NODES);
    k_agg<HEADS, HID, 4, true, 8, 128><<<agg_grid, 512, 0, stream>>>(
        u_h, f_s, f_d, i_off, i_csr, b1, u_x1);

    // Layer 2
    k_gemm_mfma<F1, F2, true><<<gemm_grid, 256, 0, stream>>>(
        u_x1, (const uint4*)pW2, asrc2, adst2, u_h, f_s, f_d, N_NODES);
    k_agg<HEADS, OUT_CH, 2, true, 8, 128><<<agg_grid, 512, 0, stream>>>(
        u_h, f_s, f_d, i_off, i_csr, b2, u_x2);

    // Pool + head (no atomics: batch is sorted -> contiguous graph ranges)
    dim3 pgrid(N_GRAPHS, POOL_SPLITS);
    k_pool_partial<<<pgrid, F2, 0, stream>>>(u_x2, i_bnd, f_prt);
    k_head<<<N_GRAPHS, F2, 0, stream>>>(f_prt, i_bnd, Wout, bout, (float*)d_out);
}